// Round 5
// baseline (854.986 us; speedup 1.0000x reference)
//
#include <hip/hip_runtime.h>
#include <hip/hip_cooperative_groups.h>
#include <math.h>

namespace cg = cooperative_groups;

#define NS   16
#define HH   512
#define WW   512
#define HW   (HH*WW)
#define TOPK 13107
#define NBIN 4096

// ---- ws word offsets. NO ATOMICS EVER TARGET d_ws (measured 100+us stalls r1/r2).
#define O_O1   0        // [16][7] squashed o1 params
#define O_O2   112      // [16][4] softmax weights
#define O_DEN  176      // [16]    sum(o2)+0.001
#define O_KN   304      // [16]    remaining k within threshold bin
#define O_A    320      // [16][3] atmospheric light
#define O_MMP  512      // [48][512] per-tile min(0:256)/max(256:512) partials
#define O_DARK 33280    // [16*512*512] f32 dark channel

// ---- d_out scratch (words; consumed before phase 4 overwrites all of out):
//   hist = out + 16HW  (16x4096 u32; atomics OK here — d_out, measured fast r2-r4)
//   part = out + 17HW  (1024 x 8 f32 asum partials)

// Gaussian weights phi/(sum+0.001), hardcoded (double-derived; ref fp32 diff ~1e-8)
#define G0 0.054466787f
#define G1 0.244103071f
#define G2 0.402457854f

__device__ __forceinline__ float tanh01(float v) { return tanhf(v)*0.5f + 0.5f; }
__device__ __forceinline__ float clamp01(float v) { return fminf(fmaxf(v, 0.0f), 1.0f); }
__device__ __forceinline__ int dark_bin(float v) {
  int b = (int)(v * (float)NBIN);
  return b > (NBIN-1) ? (NBIN-1) : (b < 0 ? 0 : b);
}

// One persistent cooperative kernel; phases separated by grid.sync().
// LDS union: phase1 minc[3680]/lh[4096] + hsum[2944]; phase2 lh[4096]+spp[256];
// phase4 xs[1440]+hb[1280]+rmn/rmx; phase5 rmn/rmx.  28.3 KB total.
__global__ void __launch_bounds__(256, 4)
k_mega(const float* __restrict__ x, float* __restrict__ wsf, unsigned* __restrict__ wsu,
       unsigned* __restrict__ hist, float* __restrict__ part, float* __restrict__ out,
       const float* __restrict__ o1, const float* __restrict__ o2) {
  cg::grid_group grid = cg::this_grid();
  __shared__ __align__(16) float sm[7040];
  __shared__ float bl[4][7];
  __shared__ int sh_bsel;
  const int tid = threadIdx.x;
  const int B = gridDim.x;
  const int bid = blockIdx.x;

  // ---------- phase 0: zero histogram ----------
  for (int i = bid*256 + tid; i < NS*NBIN/4; i += B*256) {
    uint4 zz; zz.x = 0u; zz.y = 0u; zz.z = 0u; zz.w = 0u;
    ((uint4*)hist)[i] = zz;
  }
  grid.sync();

  // ---------- phase 1: minc + 15x15 box -> dark + per-n histogram ----------
  for (int t = bid; t < 2048; t += B) {
    int w0 = (t & 7) * 64, h0 = ((t >> 3) & 15) * 32, n = t >> 7;
    float* minc = sm;
    unsigned* lh = (unsigned*)sm;
    float* hsum = sm + 4096;
    const float* xb = x + (size_t)n*3*HW;
    for (int i = tid; i < 46*20; i += 256) {
      int r = i / 20, q = i - r*20;
      int hm = h0 - 7 + r, wc = w0 - 8 + 4*q;
      float4 v; v.x = 0.f; v.y = 0.f; v.z = 0.f; v.w = 0.f;
      if (hm >= 0 && hm < HH && wc >= 0 && wc < WW) {
        size_t o = (size_t)hm*WW + wc;
        float4 a = *(const float4*)&xb[o];
        float4 b = *(const float4*)&xb[HW + o];
        float4 c = *(const float4*)&xb[2*HW + o];
        v.x = fminf(fminf(a.x,b.x),c.x); v.y = fminf(fminf(a.y,b.y),c.y);
        v.z = fminf(fminf(a.z,b.z),c.z); v.w = fminf(fminf(a.w,b.w),c.w);
      }
      *(float4*)&minc[r*80 + 4*q] = v;
    }
    __syncthreads();
    for (int i = tid; i < 46*16; i += 256) {
      int r = i >> 4, c4 = (i & 15) * 4;
      const float4* mr = (const float4*)&minc[r*80];
      int qb = c4 >> 2;
      float m[20];
      #pragma unroll
      for (int tt = 0; tt < 5; ++tt) {
        float4 v = mr[qb + tt];
        m[4*tt] = v.x; m[4*tt+1] = v.y; m[4*tt+2] = v.z; m[4*tt+3] = v.w;
      }
      float s = 0.f;
      #pragma unroll
      for (int j = 1; j <= 15; ++j) s += m[j];
      float4 o;
      o.x = s; s += m[16] - m[1];
      o.y = s; s += m[17] - m[2];
      o.z = s; s += m[18] - m[3];
      o.w = s;
      *(float4*)&hsum[r*64 + c4] = o;
    }
    __syncthreads();
    for (int i = tid; i < NBIN; i += 256) lh[i] = 0u;   // minc dead; reuse as hist
    __syncthreads();
    {
      int c = tid & 63, ty = tid >> 6, r0 = ty * 8;
      float s = 0.f;
      #pragma unroll
      for (int j = 0; j < 15; ++j) s += hsum[(r0 + j)*64 + c];
      float* dk = wsf + O_DARK + (size_t)n*HW;
      #pragma unroll
      for (int i = 0; i < 8; ++i) {
        int r = r0 + i;
        float v = s * (1.0f/225.0f);
        dk[(size_t)(h0 + r)*WW + w0 + c] = v;
        atomicAdd(&lh[dark_bin(v)], 1u);
        if (i < 7) s += hsum[(r + 15)*64 + c] - hsum[r*64 + c];
      }
    }
    __syncthreads();
    unsigned* gh = hist + n*NBIN;
    for (int i = tid; i < NBIN; i += 256) { unsigned v = lh[i]; if (v) atomicAdd(&gh[i], v); }
    __syncthreads();
  }
  __threadfence();
  grid.sync();

  // ---------- phase 2: redundant select + asum partials ----------
  for (int t = bid; t < 1024; t += B) {
    int n = t >> 6, chunk = t & 63;
    unsigned* lh = (unsigned*)sm;
    unsigned* spp = (unsigned*)(sm + 4096);
    const uint4* gh4 = (const uint4*)(hist + n*NBIN);
    unsigned ps = 0;
    #pragma unroll
    for (int k = 0; k < 4; ++k) {
      uint4 v = gh4[tid*4 + k];
      *(uint4*)&lh[tid*16 + 4*k] = v;
      ps += v.x + v.y + v.z + v.w;
    }
    spp[tid] = ps;
    __syncthreads();
    if (tid == 0) {
      const unsigned K = TOPK;
      unsigned cum = 0; int bsel = 0;
      for (int tt = 255; tt >= 0; --tt) {
        if (cum + spp[tt] >= K) {
          bsel = tt*16;
          for (int b = tt*16 + 15; b >= tt*16; --b) {
            if (cum + lh[b] >= K) { bsel = b; break; }
            cum += lh[b];
          }
          break;
        }
        cum += spp[tt];
      }
      sh_bsel = bsel;
      if (chunk == 0) wsu[O_KN + n] = K - cum;   // plain store to ws
    }
    __syncthreads();
    int bsel = sh_bsel;
    const float4* db = (const float4*)(wsf + O_DARK + (size_t)n*HW + (size_t)chunk*4096);
    const float4* x0 = (const float4*)(x + (size_t)n*3*HW + (size_t)chunk*4096);
    const float4* x1 = x0 + HW/4;
    const float4* x2 = x0 + HW/2;
    float s0=0,s1=0,s2=0,e0=0,e1=0,e2=0,ec=0;
    #pragma unroll
    for (int k = 0; k < 4; ++k) {
      int idx = k*256 + tid;
      float4 d = db[idx], a = x0[idx], b = x1[idx], c = x2[idx];
      #define ACC(DX, AX, BX, CX) { \
        int bb = dark_bin(DX); \
        bool gt = (bb > bsel), eq = (bb == bsel); \
        s0 += gt ? AX : 0.f; s1 += gt ? BX : 0.f; s2 += gt ? CX : 0.f; \
        e0 += eq ? AX : 0.f; e1 += eq ? BX : 0.f; e2 += eq ? CX : 0.f; \
        ec += eq ? 1.f : 0.f; }
      ACC(d.x, a.x, b.x, c.x) ACC(d.y, a.y, b.y, c.y)
      ACC(d.z, a.z, b.z, c.z) ACC(d.w, a.w, b.w, c.w)
      #undef ACC
    }
    #pragma unroll
    for (int off = 32; off; off >>= 1) {
      s0 += __shfl_down(s0, off); s1 += __shfl_down(s1, off); s2 += __shfl_down(s2, off);
      e0 += __shfl_down(e0, off); e1 += __shfl_down(e1, off); e2 += __shfl_down(e2, off);
      ec += __shfl_down(ec, off);
    }
    int wave = tid >> 6, lane = tid & 63;
    if (lane == 0) {
      bl[wave][0]=s0; bl[wave][1]=s1; bl[wave][2]=s2;
      bl[wave][3]=e0; bl[wave][4]=e1; bl[wave][5]=e2; bl[wave][6]=ec;
    }
    __syncthreads();
    if (tid < 7) part[t*8 + tid] = bl[0][tid] + bl[1][tid] + bl[2][tid] + bl[3][tid];
    __syncthreads();
  }
  __threadfence();
  grid.sync();

  // ---------- phase 3: fold partials -> A, params ----------
  if (bid < 16 && tid < 64) {
    int n = bid;
    const float* p = part + (size_t)(n*64 + tid)*8;
    float s0=p[0], s1=p[1], s2=p[2], e0=p[3], e1=p[4], e2=p[5], ec=p[6];
    #pragma unroll
    for (int off = 32; off; off >>= 1) {
      s0 += __shfl_down(s0, off); s1 += __shfl_down(s1, off); s2 += __shfl_down(s2, off);
      e0 += __shfl_down(e0, off); e1 += __shfl_down(e1, off); e2 += __shfl_down(e2, off);
      ec += __shfl_down(ec, off);
    }
    if (tid == 0) {
      float kn = (float)wsu[O_KN + n];
      float ce = fmaxf(ec, 1.0f);
      wsf[O_A + n*3 + 0] = (s0 + kn * (e0 / ce)) * (1.0f/(float)TOPK);
      wsf[O_A + n*3 + 1] = (s1 + kn * (e1 / ce)) * (1.0f/(float)TOPK);
      wsf[O_A + n*3 + 2] = (s2 + kn * (e2 / ce)) * (1.0f/(float)TOPK);
      wsf[O_O1+n*7+0] = tanh01(o1[n*7+0])*0.25f + 1.0f;
      wsf[O_O1+n*7+1] = tanh01(o1[n*7+1])*0.9f  + 0.1f;
      wsf[O_O1+n*7+2] = tanh01(o1[n*7+2])*2.0f;
      wsf[O_O1+n*7+3] = tanh01(o1[n*7+3]);
      wsf[O_O1+n*7+4] = tanh01(o1[n*7+4])*0.1f + 0.95f;
      wsf[O_O1+n*7+5] = tanh01(o1[n*7+5])*0.1f + 0.95f;
      wsf[O_O1+n*7+6] = tanh01(o1[n*7+6])*0.1f + 0.95f;
      float q0 = expf(tanh01(o2[n*4+0]));
      float q1 = expf(tanh01(o2[n*4+1]));
      float q2 = expf(tanh01(o2[n*4+2]));
      float q3 = expf(tanh01(o2[n*4+3]));
      float s = q0+q1+q2+q3;
      q0 /= s; q1 /= s; q2 /= s; q3 /= s;
      wsf[O_O2+n*4+0]=q0; wsf[O_O2+n*4+1]=q1; wsf[O_O2+n*4+2]=q2; wsf[O_O2+n*4+3]=q3;
      wsf[O_DEN+n] = (q0+q1+q2+q3) + 0.001f;
    }
  }
  __threadfence();
  grid.sync();

  // ---------- phase 4: fused per-pixel (writes unnormalized out + min/max partials) ----------
  for (int t = bid; t < 12288; t += B) {
    int w0 = (t & 7) * 64, h0 = ((t >> 3) & 31) * 16, z = t >> 8;
    int n = z / 3, c = z - n*3;
    float* xs = sm;            // 20*72
    float* hb = sm + 1440;     // 20*64
    float* rmn = sm + 2720;    // 4
    float* rmx = sm + 2724;    // 4
    const float* xc = x + (size_t)z*HW;
    for (int i = tid; i < 360; i += 256) {
      int r = i / 18, q = i - r*18;
      int gh = h0 - 2 + r, gw = w0 - 4 + 4*q;
      float4 v; v.x = 0.f; v.y = 0.f; v.z = 0.f; v.w = 0.f;
      if (gh >= 0 && gh < HH && gw >= 0 && gw < WW)
        v = *(const float4*)&xc[(size_t)gh*WW + gw];
      *(float4*)&xs[r*72 + 4*q] = v;
    }
    __syncthreads();
    for (int i = tid; i < 320; i += 256) {
      int r = i >> 4, c4 = (i & 15) * 4;
      const float4* xr = (const float4*)&xs[r*72];
      int qb = c4 >> 2;
      float4 A4 = xr[qb], B4 = xr[qb+1], C4 = xr[qb+2];
      float m2=A4.z, m3=A4.w, m4=B4.x, m5=B4.y, m6=B4.z, m7=B4.w, m8=C4.x, m9=C4.y;
      float4 o;
      o.x = G0*(m2+m6) + G1*(m3+m5) + G2*m4;
      o.y = G0*(m3+m7) + G1*(m4+m6) + G2*m5;
      o.z = G0*(m4+m8) + G1*(m5+m7) + G2*m6;
      o.w = G0*(m5+m9) + G1*(m6+m8) + G2*m7;
      *(float4*)&hb[r*64 + c4] = o;
    }
    __syncthreads();
    float param = wsf[O_O1 + n*7 + 0];
    float lamda = wsf[O_O1 + n*7 + 2];
    float wpar  = wsf[O_O1 + n*7 + 3];
    float wb    = wsf[O_O1 + n*7 + 4 + c];
    float q0 = wsf[O_O2 + n*4 + 0], q1 = wsf[O_O2 + n*4 + 1];
    float q2 = wsf[O_O2 + n*4 + 2], q3 = wsf[O_O2 + n*4 + 3];
    float rden = 1.0f / wsf[O_DEN + n];
    float A   = wsf[O_A + n*3 + c];
    int r = tid >> 4, c4 = (tid & 15) * 4;
    float4 xv = *(const float4*)&xs[(r+2)*72 + c4 + 4];
    float4 b0 = *(const float4*)&hb[(r+0)*64 + c4];
    float4 b1 = *(const float4*)&hb[(r+1)*64 + c4];
    float4 b2 = *(const float4*)&hb[(r+2)*64 + c4];
    float4 b3 = *(const float4*)&hb[(r+3)*64 + c4];
    float4 b4 = *(const float4*)&hb[(r+4)*64 + c4];
    const float* dark = wsf + O_DARK + (size_t)n*HW;
    float4 dk = *(const float4*)&dark[(size_t)(h0+r)*WW + w0 + c4];
    float4 osum;
    float mnv = 3.4e38f, mxv = -3.4e38f;
    #define PIX(OX, XV, B0, B1, B2, B3, B4, DK) { \
      float blur = clamp01(G0*(B0+B4) + G1*(B1+B3) + G2*B2); \
      float x4v = clamp01(XV + lamda*(XV - blur)); \
      float x1v = clamp01(XV * wb); \
      float x2v = clamp01(__expf(param*__logf(XV)) + 0.001f); \
      float tr = 1.0f - wpar*DK; tr = tr > 0.1f ? tr : 0.1f; \
      float x5v = clamp01((XV - A)/(tr + 0.001f) + A); \
      OX = (XV + 0.1f*(q0*x1v + q1*x2v + q2*x4v + q3*x5v)) * rden; \
      mnv = fminf(mnv, OX); mxv = fmaxf(mxv, OX); }
    PIX(osum.x, xv.x, b0.x, b1.x, b2.x, b3.x, b4.x, dk.x)
    PIX(osum.y, xv.y, b0.y, b1.y, b2.y, b3.y, b4.y, dk.y)
    PIX(osum.z, xv.z, b0.z, b1.z, b2.z, b3.z, b4.z, dk.z)
    PIX(osum.w, xv.w, b0.w, b1.w, b2.w, b3.w, b4.w, dk.w)
    #undef PIX
    *(float4*)&out[(size_t)z*HW + (size_t)(h0+r)*WW + w0 + c4] = osum;
    #pragma unroll
    for (int off = 32; off; off >>= 1) {
      mnv = fminf(mnv, __shfl_down(mnv, off));
      mxv = fmaxf(mxv, __shfl_down(mxv, off));
    }
    int wave = tid >> 6, lane = tid & 63;
    if (lane == 0) { rmn[wave] = mnv; rmx[wave] = mxv; }
    __syncthreads();
    if (tid == 0) {
      mnv = fminf(fminf(rmn[0], rmn[1]), fminf(rmn[2], rmn[3]));
      mxv = fmaxf(fmaxf(rmx[0], rmx[1]), fmaxf(rmx[2], rmx[3]));
      int bxy = t & 255;
      wsf[O_MMP + z*512 + bxy]       = mnv;   // plain stores to ws
      wsf[O_MMP + z*512 + 256 + bxy] = mxv;
    }
    __syncthreads();
  }
  __threadfence();
  grid.sync();

  // ---------- phase 5: redundant min/max fold + normalize (out re-read hits L3) ----------
  for (int t = bid; t < 12288; t += B) {
    int nc = t >> 8;
    float* rmn = sm;
    float* rmx = sm + 4;
    float mn = wsf[O_MMP + nc*512 + tid];
    float mx = wsf[O_MMP + nc*512 + 256 + tid];
    #pragma unroll
    for (int off = 32; off; off >>= 1) {
      mn = fminf(mn, __shfl_down(mn, off));
      mx = fmaxf(mx, __shfl_down(mx, off));
    }
    int wave = tid >> 6, lane = tid & 63;
    if (lane == 0) { rmn[wave] = mn; rmx[wave] = mx; }
    __syncthreads();
    mn = fminf(fminf(rmn[0], rmn[1]), fminf(rmn[2], rmn[3]));
    mx = fmaxf(fmaxf(rmx[0], rmx[1]), fmaxf(rmx[2], rmx[3]));
    float sc = 1.0f / (mx - mn + 1e-7f);
    int i4 = t*256 + tid;
    float4 v = ((const float4*)out)[i4];
    v.x = (v.x - mn) * sc; v.y = (v.y - mn) * sc;
    v.z = (v.z - mn) * sc; v.w = (v.w - mn) * sc;
    ((float4*)out)[i4] = v;
    __syncthreads();
  }
}

extern "C" void kernel_launch(void* const* d_in, const int* in_sizes, int n_in,
                              void* d_out, int out_size, void* d_ws, size_t ws_size,
                              hipStream_t stream) {
  const float* x  = (const float*)d_in[0];
  const float* o1 = (const float*)d_in[1];
  const float* o2 = (const float*)d_in[2];
  float* out = (float*)d_out;
  float* wsf = (float*)d_ws;
  unsigned* wsu = (unsigned*)d_ws;
  unsigned* hist = (unsigned*)(out + (size_t)16*HW);   // d_out scratch (inside out; dead by phase 4)
  float* part = out + (size_t)17*HW;                   // d_out scratch

  int maxb = 0;
  hipOccupancyMaxActiveBlocksPerMultiprocessor(&maxb, reinterpret_cast<const void*>(k_mega), 256, 0);
  int B = maxb * 256;            // 256 CUs on MI355X
  if (B > 2048) B = 2048;
  if (B < 256)  B = 256;

  void* args[] = { (void*)&x, (void*)&wsf, (void*)&wsu, (void*)&hist,
                   (void*)&part, (void*)&out, (void*)&o1, (void*)&o2 };
  hipLaunchCooperativeKernel(reinterpret_cast<const void*>(k_mega),
                             dim3(B), dim3(256), args, 0, stream);
}

// Round 6
// 306.468 us; speedup vs baseline: 2.7898x; 2.7898x over previous
//
#include <hip/hip_runtime.h>
#include <math.h>

#define NS   16
#define HH   512
#define WW   512
#define HW   (HH*WW)
#define TOPK 13107
#define NBIN 4096

// ---- ws word offsets. NO ATOMICS EVER TARGET d_ws (measured 100+us stalls r1/r2).
// ---- NO cooperative/persistent kernel (measured 1.1ms, 263 GB/s effective, r5).
#define O_O1   0        // [16][7] squashed o1 params
#define O_O2   112      // [16][4] softmax weights
#define O_DEN  176      // [16]    sum(o2)+0.001
#define O_BSEL 288      // [16]    selected threshold bin
#define O_KN   304      // [16]    remaining k within threshold bin
#define O_A    320      // [16][3] atmospheric light
#define O_MIN  368      // [48]    final per-(n,c) min
#define O_MAX  416      // [48]    final per-(n,c) max
#define O_MMP  512      // [48][512] per-tile min(0:256)/max(256:512) partials
#define O_DARK 33280    // [16*512*512] f32 dark channel

// ---- d_out scratch (words; consumed before k_main overwrites all of out):
//   hist = out + 16HW  (16x4096 u32; atomics OK here — d_out, measured fast r2-r4)
//   part = out + 17HW  (1024 x 8 f32 asum partials)

// Gaussian weights phi/(sum+0.001), hardcoded (double-derived; ref fp32 diff ~1e-8)
#define G0 0.054466787f
#define G1 0.244103071f
#define G2 0.402457854f

__device__ __forceinline__ float tanh01(float v) { return tanhf(v)*0.5f + 0.5f; }
__device__ __forceinline__ float clamp01(float v) { return fminf(fmaxf(v, 0.0f), 1.0f); }
__device__ __forceinline__ int dark_bin(float v) {
  int b = (int)(v * (float)NBIN);
  return b > (NBIN-1) ? (NBIN-1) : (b < 0 ? 0 : b);
}

// ---------------- zero histogram ----------------
__global__ void k_zero(unsigned* __restrict__ hist) {
  int i = blockIdx.x * 256 + threadIdx.x;       // 16384 uint4 = 65536 words
  uint4 z; z.x = 0u; z.y = 0u; z.z = 0u; z.w = 0u;
  ((uint4*)hist)[i] = z;
}

// ---------------- fused minc + 15x15 box filter + histogram ----------------
// block: 64x32 dark tile. grid (8,16,16).
__global__ void __launch_bounds__(256)
k_dark(const float* __restrict__ x, float* __restrict__ wsf, unsigned* __restrict__ hist) {
  __shared__ __align__(16) float sm[4096 + 46*64];   // union(minc[46*80]=3680, lh[4096]) + hsum[46*64]
  float* minc = sm;
  unsigned* lh = (unsigned*)sm;
  float* hsum = sm + 4096;
  int tid = threadIdx.x;
  int w0 = blockIdx.x * 64, h0 = blockIdx.y * 32, n = blockIdx.z;
  const float* xb = x + (size_t)n*3*HW;

  // stage minc rows [h0-7,h0+39) cols [w0-8,w0+72), zero outside (box filter zero-pads)
  for (int i = tid; i < 46*20; i += 256) {
    int r = i / 20, q = i - r*20;
    int hm = h0 - 7 + r, wc = w0 - 8 + 4*q;
    float4 v; v.x = 0.f; v.y = 0.f; v.z = 0.f; v.w = 0.f;
    if (hm >= 0 && hm < HH && wc >= 0 && wc < WW) {
      size_t o = (size_t)hm*WW + wc;
      float4 a = *(const float4*)&xb[o];
      float4 b = *(const float4*)&xb[HW + o];
      float4 c = *(const float4*)&xb[2*HW + o];
      v.x = fminf(fminf(a.x,b.x),c.x); v.y = fminf(fminf(a.y,b.y),c.y);
      v.z = fminf(fminf(a.z,b.z),c.z); v.w = fminf(fminf(a.w,b.w),c.w);
    }
    *(float4*)&minc[r*80 + 4*q] = v;
  }
  __syncthreads();
  // horizontal 15-tap sum
  for (int i = tid; i < 46*16; i += 256) {
    int r = i >> 4, c4 = (i & 15) * 4;
    const float4* mr = (const float4*)&minc[r*80];
    int qb = c4 >> 2;
    float m[20];
    #pragma unroll
    for (int t = 0; t < 5; ++t) {
      float4 v = mr[qb + t];
      m[4*t] = v.x; m[4*t+1] = v.y; m[4*t+2] = v.z; m[4*t+3] = v.w;
    }
    float s = 0.f;
    #pragma unroll
    for (int j = 1; j <= 15; ++j) s += m[j];
    float4 o;
    o.x = s; s += m[16] - m[1];
    o.y = s; s += m[17] - m[2];
    o.z = s; s += m[18] - m[3];
    o.w = s;
    *(float4*)&hsum[r*64 + c4] = o;
  }
  __syncthreads();
  for (int i = tid; i < NBIN; i += 256) lh[i] = 0u;   // minc dead; reuse as hist
  __syncthreads();
  // vertical 15-tap sliding sum -> dark; wave-aggregated bin counts
  // (ballot-leader: waves span 1-3 bins here, so 1-3 iterations — avoids
  //  64-way same-address LDS atomic serialization from adjacent columns)
  {
    int c = tid & 63, ty = tid >> 6, r0 = ty * 8;
    int lane = tid & 63;
    float s = 0.f;
    #pragma unroll
    for (int j = 0; j < 15; ++j) s += hsum[(r0 + j)*64 + c];
    float* dk = wsf + O_DARK + (size_t)n*HW;
    #pragma unroll
    for (int i = 0; i < 8; ++i) {
      int r = r0 + i;
      float v = s * (1.0f/225.0f);
      dk[(size_t)(h0 + r)*WW + w0 + c] = v;
      int b = dark_bin(v);
      bool need = true;
      while (__any(need)) {
        unsigned long long mn = __ballot(need);
        int src = __ffsll(mn) - 1;
        int bsel = __shfl(b, src);
        bool same = need && (b == bsel);
        unsigned long long mm = __ballot(same);
        if (lane == src) atomicAdd(&lh[bsel], (unsigned)__popcll(mm));
        if (same) need = false;
      }
      if (i < 7) s += hsum[(r + 15)*64 + c] - hsum[r*64 + c];
    }
  }
  __syncthreads();
  unsigned* gh = hist + n*NBIN;
  for (int i = tid; i < NBIN; i += 256) { unsigned v = lh[i]; if (v) atomicAdd(&gh[i], v); }
}

// ---------------- threshold-bin choose (16 blocks, once) ----------------
__global__ void k_select(const unsigned* __restrict__ hist, unsigned* __restrict__ wsu) {
  int n = blockIdx.x, tid = threadIdx.x;
  const unsigned* gh = hist + n*NBIN;
  __shared__ __align__(16) unsigned lh[NBIN];
  __shared__ unsigned spp[256];
  const uint4* gh4 = (const uint4*)gh;
  unsigned ps = 0;
  #pragma unroll
  for (int k = 0; k < 4; ++k) {
    uint4 v = gh4[tid*4 + k];
    *(uint4*)&lh[tid*16 + 4*k] = v;
    ps += v.x + v.y + v.z + v.w;
  }
  spp[tid] = ps;
  __syncthreads();
  if (tid == 0) {
    const unsigned K = TOPK;
    unsigned cum = 0; int bsel = 0;
    for (int t = 255; t >= 0; --t) {
      if (cum + spp[t] >= K) {
        bsel = t*16;
        for (int b = t*16 + 15; b >= t*16; --b) {
          if (cum + lh[b] >= K) { bsel = b; break; }
          cum += lh[b];
        }
        break;
      }
      cum += spp[t];
    }
    wsu[O_BSEL + n] = (unsigned)bsel;   // plain stores to ws: fine
    wsu[O_KN + n]   = K - cum;
  }
}

// ---------------- atmospheric-light partial sums (branchless, streaming) ----------------
__global__ void __launch_bounds__(256)
k_asum(const float* __restrict__ x, const float* __restrict__ wsf,
       const unsigned* __restrict__ wsu, float* __restrict__ part) {
  __shared__ float bl[4][7];
  int tid = threadIdx.x;
  int n = blockIdx.x >> 6, chunk = blockIdx.x & 63;
  int bsel = (int)wsu[O_BSEL + n];
  const float4* db = (const float4*)(wsf + O_DARK + (size_t)n*HW + (size_t)chunk*4096);
  const float4* x0 = (const float4*)(x + (size_t)n*3*HW + (size_t)chunk*4096);
  const float4* x1 = x0 + HW/4;
  const float4* x2 = x0 + HW/2;
  float s0=0,s1=0,s2=0,e0=0,e1=0,e2=0,ec=0;
  #pragma unroll
  for (int k = 0; k < 4; ++k) {
    int idx = k*256 + tid;
    float4 d = db[idx], a = x0[idx], b = x1[idx], c = x2[idx];
    #define ACC(DX, AX, BX, CX) { \
      int bb = dark_bin(DX); \
      bool gt = (bb > bsel), eq = (bb == bsel); \
      s0 += gt ? AX : 0.f; s1 += gt ? BX : 0.f; s2 += gt ? CX : 0.f; \
      e0 += eq ? AX : 0.f; e1 += eq ? BX : 0.f; e2 += eq ? CX : 0.f; \
      ec += eq ? 1.f : 0.f; }
    ACC(d.x, a.x, b.x, c.x) ACC(d.y, a.y, b.y, c.y)
    ACC(d.z, a.z, b.z, c.z) ACC(d.w, a.w, b.w, c.w)
    #undef ACC
  }
  #pragma unroll
  for (int off = 32; off; off >>= 1) {
    s0 += __shfl_down(s0, off); s1 += __shfl_down(s1, off); s2 += __shfl_down(s2, off);
    e0 += __shfl_down(e0, off); e1 += __shfl_down(e1, off); e2 += __shfl_down(e2, off);
    ec += __shfl_down(ec, off);
  }
  int wave = tid >> 6, lane = tid & 63;
  if (lane == 0) {
    bl[wave][0]=s0; bl[wave][1]=s1; bl[wave][2]=s2;
    bl[wave][3]=e0; bl[wave][4]=e1; bl[wave][5]=e2; bl[wave][6]=ec;
  }
  __syncthreads();
  if (tid < 7) part[blockIdx.x*8 + tid] = bl[0][tid] + bl[1][tid] + bl[2][tid] + bl[3][tid];
}

// ---------------- fold partials -> A, plus param squashing ----------------
__global__ void k_areduce(const float* __restrict__ part, const unsigned* __restrict__ wsu,
                          float* __restrict__ wsf, const float* __restrict__ o1,
                          const float* __restrict__ o2) {
  int n = blockIdx.x, t = threadIdx.x;  // 64 threads = 64 chunks
  const float* p = part + (size_t)(n*64 + t)*8;
  float s0=p[0], s1=p[1], s2=p[2], e0=p[3], e1=p[4], e2=p[5], ec=p[6];
  #pragma unroll
  for (int off = 32; off; off >>= 1) {
    s0 += __shfl_down(s0, off); s1 += __shfl_down(s1, off); s2 += __shfl_down(s2, off);
    e0 += __shfl_down(e0, off); e1 += __shfl_down(e1, off); e2 += __shfl_down(e2, off);
    ec += __shfl_down(ec, off);
  }
  if (t == 0) {
    float kn = (float)wsu[O_KN + n];
    float ce = fmaxf(ec, 1.0f);
    wsf[O_A + n*3 + 0] = (s0 + kn * (e0 / ce)) * (1.0f/(float)TOPK);
    wsf[O_A + n*3 + 1] = (s1 + kn * (e1 / ce)) * (1.0f/(float)TOPK);
    wsf[O_A + n*3 + 2] = (s2 + kn * (e2 / ce)) * (1.0f/(float)TOPK);
    wsf[O_O1+n*7+0] = tanh01(o1[n*7+0])*0.25f + 1.0f;
    wsf[O_O1+n*7+1] = tanh01(o1[n*7+1])*0.9f  + 0.1f;
    wsf[O_O1+n*7+2] = tanh01(o1[n*7+2])*2.0f;
    wsf[O_O1+n*7+3] = tanh01(o1[n*7+3]);
    wsf[O_O1+n*7+4] = tanh01(o1[n*7+4])*0.1f + 0.95f;
    wsf[O_O1+n*7+5] = tanh01(o1[n*7+5])*0.1f + 0.95f;
    wsf[O_O1+n*7+6] = tanh01(o1[n*7+6])*0.1f + 0.95f;
    float q0 = expf(tanh01(o2[n*4+0]));
    float q1 = expf(tanh01(o2[n*4+1]));
    float q2 = expf(tanh01(o2[n*4+2]));
    float q3 = expf(tanh01(o2[n*4+3]));
    float s = q0+q1+q2+q3;
    q0 /= s; q1 /= s; q2 /= s; q3 /= s;
    wsf[O_O2+n*4+0]=q0; wsf[O_O2+n*4+1]=q1; wsf[O_O2+n*4+2]=q2; wsf[O_O2+n*4+3]=q3;
    wsf[O_DEN+n] = (q0+q1+q2+q3) + 0.001f;
  }
}

// ---------------- fused per-pixel kernel, float4 per thread ----------------
__global__ void __launch_bounds__(256)
k_main(const float* __restrict__ x, float* __restrict__ wsf, float* __restrict__ out) {
  __shared__ __align__(16) float xs[20*72];   // rows h0-2..h0+17, cols w0-4..w0+67
  __shared__ __align__(16) float hb[20*64];   // horizontal blur
  __shared__ float rmn[4], rmx[4];
  int tid = threadIdx.x;
  int w0 = blockIdx.x * 64, h0 = blockIdx.y * 16;
  int z = blockIdx.z, n = z / 3, c = z % 3;
  const float* xc = x + (size_t)z*HW;
  for (int i = tid; i < 360; i += 256) {
    int r = i / 18, q = i - r*18;
    int gh = h0 - 2 + r, gw = w0 - 4 + 4*q;
    float4 v; v.x = 0.f; v.y = 0.f; v.z = 0.f; v.w = 0.f;
    if (gh >= 0 && gh < HH && gw >= 0 && gw < WW)
      v = *(const float4*)&xc[(size_t)gh*WW + gw];
    *(float4*)&xs[r*72 + 4*q] = v;
  }
  __syncthreads();
  for (int i = tid; i < 320; i += 256) {
    int r = i >> 4, c4 = (i & 15) * 4;
    const float4* xr = (const float4*)&xs[r*72];
    int qb = c4 >> 2;
    float4 A4 = xr[qb], B4 = xr[qb+1], C4 = xr[qb+2];
    float m2=A4.z, m3=A4.w, m4=B4.x, m5=B4.y, m6=B4.z, m7=B4.w, m8=C4.x, m9=C4.y;
    float4 o;
    o.x = G0*(m2+m6) + G1*(m3+m5) + G2*m4;
    o.y = G0*(m3+m7) + G1*(m4+m6) + G2*m5;
    o.z = G0*(m4+m8) + G1*(m5+m7) + G2*m6;
    o.w = G0*(m5+m9) + G1*(m6+m8) + G2*m7;
    *(float4*)&hb[r*64 + c4] = o;
  }
  __syncthreads();
  float param = wsf[O_O1 + n*7 + 0];
  float lamda = wsf[O_O1 + n*7 + 2];
  float wpar  = wsf[O_O1 + n*7 + 3];
  float wb    = wsf[O_O1 + n*7 + 4 + c];
  float q0 = wsf[O_O2 + n*4 + 0], q1 = wsf[O_O2 + n*4 + 1];
  float q2 = wsf[O_O2 + n*4 + 2], q3 = wsf[O_O2 + n*4 + 3];
  float rden = 1.0f / wsf[O_DEN + n];
  float A   = wsf[O_A + n*3 + c];
  int r = tid >> 4, c4 = (tid & 15) * 4;
  float4 xv = *(const float4*)&xs[(r+2)*72 + c4 + 4];
  float4 b0 = *(const float4*)&hb[(r+0)*64 + c4];
  float4 b1 = *(const float4*)&hb[(r+1)*64 + c4];
  float4 b2 = *(const float4*)&hb[(r+2)*64 + c4];
  float4 b3 = *(const float4*)&hb[(r+3)*64 + c4];
  float4 b4 = *(const float4*)&hb[(r+4)*64 + c4];
  const float* dark = wsf + O_DARK + (size_t)n*HW;
  float4 dk = *(const float4*)&dark[(size_t)(h0+r)*WW + w0 + c4];
  float4 osum;
  float mnv = 3.4e38f, mxv = -3.4e38f;
  #define PIX(OX, XV, B0, B1, B2, B3, B4, DK) { \
    float blur = clamp01(G0*(B0+B4) + G1*(B1+B3) + G2*B2); \
    float x4v = clamp01(XV + lamda*(XV - blur)); \
    float x1v = clamp01(XV * wb); \
    float x2v = clamp01(__expf(param*__logf(XV)) + 0.001f); \
    float tr = 1.0f - wpar*DK; tr = tr > 0.1f ? tr : 0.1f; \
    float x5v = clamp01((XV - A)/(tr + 0.001f) + A); \
    OX = (XV + 0.1f*(q0*x1v + q1*x2v + q2*x4v + q3*x5v)) * rden; \
    mnv = fminf(mnv, OX); mxv = fmaxf(mxv, OX); }
  PIX(osum.x, xv.x, b0.x, b1.x, b2.x, b3.x, b4.x, dk.x)
  PIX(osum.y, xv.y, b0.y, b1.y, b2.y, b3.y, b4.y, dk.y)
  PIX(osum.z, xv.z, b0.z, b1.z, b2.z, b3.z, b4.z, dk.z)
  PIX(osum.w, xv.w, b0.w, b1.w, b2.w, b3.w, b4.w, dk.w)
  #undef PIX
  *(float4*)&out[(size_t)z*HW + (size_t)(h0+r)*WW + w0 + c4] = osum;
  #pragma unroll
  for (int off = 32; off; off >>= 1) {
    mnv = fminf(mnv, __shfl_down(mnv, off));
    mxv = fmaxf(mxv, __shfl_down(mxv, off));
  }
  int wave = tid >> 6, lane = tid & 63;
  if (lane == 0) { rmn[wave] = mnv; rmx[wave] = mxv; }
  __syncthreads();
  if (tid == 0) {
    mnv = fminf(fminf(rmn[0], rmn[1]), fminf(rmn[2], rmn[3]));
    mxv = fmaxf(fmaxf(rmx[0], rmx[1]), fmaxf(rmx[2], rmx[3]));
    int bxy = blockIdx.y * 8 + blockIdx.x;
    wsf[O_MMP + z*512 + bxy]       = mnv;   // plain stores to ws
    wsf[O_MMP + z*512 + 256 + bxy] = mxv;
  }
}

// ---------------- fold min/max partials (48 blocks, once) ----------------
__global__ void k_mmred(float* __restrict__ wsf) {
  int z = blockIdx.x, tid = threadIdx.x;
  __shared__ float rmn[4], rmx[4];
  float mn = wsf[O_MMP + z*512 + tid];
  float mx = wsf[O_MMP + z*512 + 256 + tid];
  #pragma unroll
  for (int off = 32; off; off >>= 1) {
    mn = fminf(mn, __shfl_down(mn, off));
    mx = fmaxf(mx, __shfl_down(mx, off));
  }
  int wave = tid >> 6, lane = tid & 63;
  if (lane == 0) { rmn[wave] = mn; rmx[wave] = mx; }
  __syncthreads();
  if (tid == 0) {
    wsf[O_MIN + z] = fminf(fminf(rmn[0], rmn[1]), fminf(rmn[2], rmn[3]));
    wsf[O_MAX + z] = fmaxf(fmaxf(rmx[0], rmx[1]), fmaxf(rmx[2], rmx[3]));
  }
}

// ---------------- normalization: pure stream, 8 float4/thread ----------------
__global__ void __launch_bounds__(256)
k_norm(float* __restrict__ out, const float* __restrict__ wsf) {
  int nc = blockIdx.x >> 5;          // 32 blocks per (n,c), 2048 f4 each
  int sub = blockIdx.x & 31;
  float mn = wsf[O_MIN + nc];
  float mx = wsf[O_MAX + nc];
  float sc = 1.0f / (mx - mn + 1e-7f);
  float4* o4 = (float4*)out + (size_t)nc*65536 + (size_t)sub*2048;
  int tid = threadIdx.x;
  #pragma unroll
  for (int k = 0; k < 8; ++k) {
    float4 v = o4[k*256 + tid];
    v.x = (v.x - mn) * sc; v.y = (v.y - mn) * sc;
    v.z = (v.z - mn) * sc; v.w = (v.w - mn) * sc;
    o4[k*256 + tid] = v;
  }
}

extern "C" void kernel_launch(void* const* d_in, const int* in_sizes, int n_in,
                              void* d_out, int out_size, void* d_ws, size_t ws_size,
                              hipStream_t stream) {
  const float* x  = (const float*)d_in[0];
  const float* o1 = (const float*)d_in[1];
  const float* o2 = (const float*)d_in[2];
  float* out = (float*)d_out;
  float* wsf = (float*)d_ws;
  unsigned* wsu = (unsigned*)d_ws;
  unsigned* hist = (unsigned*)(out + (size_t)16*HW);   // d_out scratch
  float* part = out + (size_t)17*HW;                   // d_out scratch

  k_zero<<<dim3(64), dim3(256), 0, stream>>>(hist);
  k_dark<<<dim3(8, 16, 16), dim3(256), 0, stream>>>(x, wsf, hist);
  k_select<<<dim3(16), dim3(256), 0, stream>>>(hist, wsu);
  k_asum<<<dim3(1024), dim3(256), 0, stream>>>(x, wsf, wsu, part);
  k_areduce<<<dim3(16), dim3(64), 0, stream>>>(part, wsu, wsf, o1, o2);
  k_main<<<dim3(8, 32, 48), dim3(256), 0, stream>>>(x, wsf, out);
  k_mmred<<<dim3(48), dim3(256), 0, stream>>>(wsf);
  k_norm<<<dim3(1536), dim3(256), 0, stream>>>(out, wsf);
}

// Round 7
// 195.191 us; speedup vs baseline: 4.3803x; 1.5701x over previous
//
#include <hip/hip_runtime.h>
#include <math.h>

#define NS   16
#define HH   512
#define WW   512
#define HW   (HH*WW)
#define TOPK 13107
#define NBIN 4096

// ---- ws word offsets. NO ATOMICS EVER TARGET d_ws (measured 100+us stalls r1/r2).
// ---- NO cooperative/persistent kernel (measured 1.1ms, 263 GB/s effective, r5).
// ---- NO ballot-leader aggregation for smooth value-domain bins (r6: 157us k_dark;
//      serial per-distinct-bin cross-lane chain. Plain LDS atomicAdd is fast, r4).
#define O_O1   0        // [16][7] squashed o1 params
#define O_O2   112      // [16][4] softmax weights
#define O_DEN  176      // [16]    sum(o2)+0.001
#define O_BSEL 288      // [16]    selected threshold bin
#define O_KN   304      // [16]    remaining k within threshold bin
#define O_A    320      // [16][3] atmospheric light
#define O_MIN  368      // [48]    final per-(n,c) min
#define O_MAX  416      // [48]    final per-(n,c) max
#define O_MMP  512      // [48][512] per-tile min(0:256)/max(256:512) partials
#define O_DARK 33280    // [16*512*512] f32 dark channel

// ---- d_out scratch (words; consumed before k_main overwrites all of out):
//   hist = out + 16HW  (16x4096 u32; atomics OK here — d_out, measured fast r2-r4)
//   part = out + 17HW  (1024 x 8 f32 asum partials)

// Gaussian weights phi/(sum+0.001), hardcoded (double-derived; ref fp32 diff ~1e-8)
#define G0 0.054466787f
#define G1 0.244103071f
#define G2 0.402457854f

__device__ __forceinline__ float tanh01(float v) { return tanhf(v)*0.5f + 0.5f; }
__device__ __forceinline__ float clamp01(float v) { return fminf(fmaxf(v, 0.0f), 1.0f); }
__device__ __forceinline__ int dark_bin(float v) {
  int b = (int)(v * (float)NBIN);
  return b > (NBIN-1) ? (NBIN-1) : (b < 0 ? 0 : b);
}

// ---------------- zero histogram ----------------
__global__ void k_zero(unsigned* __restrict__ hist) {
  int i = blockIdx.x * 256 + threadIdx.x;       // 16384 uint4 = 65536 words
  uint4 z; z.x = 0u; z.y = 0u; z.z = 0u; z.w = 0u;
  ((uint4*)hist)[i] = z;
}

// ---------------- fused minc + 15x15 box filter + histogram ----------------
// block: 64x32 dark tile. grid (8,16,16).
__global__ void __launch_bounds__(256)
k_dark(const float* __restrict__ x, float* __restrict__ wsf, unsigned* __restrict__ hist) {
  __shared__ __align__(16) float sm[4096 + 46*64];   // union(minc[46*80]=3680, lh[4096]) + hsum[46*64]
  float* minc = sm;
  unsigned* lh = (unsigned*)sm;
  float* hsum = sm + 4096;
  int tid = threadIdx.x;
  int w0 = blockIdx.x * 64, h0 = blockIdx.y * 32, n = blockIdx.z;
  const float* xb = x + (size_t)n*3*HW;

  // stage minc rows [h0-7,h0+39) cols [w0-8,w0+72), zero outside (box filter zero-pads)
  for (int i = tid; i < 46*20; i += 256) {
    int r = i / 20, q = i - r*20;
    int hm = h0 - 7 + r, wc = w0 - 8 + 4*q;
    float4 v; v.x = 0.f; v.y = 0.f; v.z = 0.f; v.w = 0.f;
    if (hm >= 0 && hm < HH && wc >= 0 && wc < WW) {
      size_t o = (size_t)hm*WW + wc;
      float4 a = *(const float4*)&xb[o];
      float4 b = *(const float4*)&xb[HW + o];
      float4 c = *(const float4*)&xb[2*HW + o];
      v.x = fminf(fminf(a.x,b.x),c.x); v.y = fminf(fminf(a.y,b.y),c.y);
      v.z = fminf(fminf(a.z,b.z),c.z); v.w = fminf(fminf(a.w,b.w),c.w);
    }
    *(float4*)&minc[r*80 + 4*q] = v;
  }
  __syncthreads();
  // horizontal 15-tap sum
  for (int i = tid; i < 46*16; i += 256) {
    int r = i >> 4, c4 = (i & 15) * 4;
    const float4* mr = (const float4*)&minc[r*80];
    int qb = c4 >> 2;
    float m[20];
    #pragma unroll
    for (int t = 0; t < 5; ++t) {
      float4 v = mr[qb + t];
      m[4*t] = v.x; m[4*t+1] = v.y; m[4*t+2] = v.z; m[4*t+3] = v.w;
    }
    float s = 0.f;
    #pragma unroll
    for (int j = 1; j <= 15; ++j) s += m[j];
    float4 o;
    o.x = s; s += m[16] - m[1];
    o.y = s; s += m[17] - m[2];
    o.z = s; s += m[18] - m[3];
    o.w = s;
    *(float4*)&hsum[r*64 + c4] = o;
  }
  __syncthreads();
  for (int i = tid; i < NBIN; i += 256) lh[i] = 0u;   // minc dead; reuse as hist
  __syncthreads();
  // vertical 15-tap sliding sum -> dark; plain LDS atomics with vertical
  // run-length pre-aggregation (dark smooth in h: ~2-4 flushes per 8 rows)
  {
    int c = tid & 63, ty = tid >> 6, r0 = ty * 8;
    float s = 0.f;
    #pragma unroll
    for (int j = 0; j < 15; ++j) s += hsum[(r0 + j)*64 + c];
    float* dk = wsf + O_DARK + (size_t)n*HW;
    int prevb = -1; unsigned cnt = 0;
    #pragma unroll
    for (int i = 0; i < 8; ++i) {
      int r = r0 + i;
      float v = s * (1.0f/225.0f);
      dk[(size_t)(h0 + r)*WW + w0 + c] = v;
      int b = dark_bin(v);
      if (b == prevb) { cnt++; }
      else {
        if (cnt) atomicAdd(&lh[prevb], cnt);
        prevb = b; cnt = 1u;
      }
      if (i < 7) s += hsum[(r + 15)*64 + c] - hsum[r*64 + c];
    }
    if (cnt) atomicAdd(&lh[prevb], cnt);
  }
  __syncthreads();
  unsigned* gh = hist + n*NBIN;
  for (int i = tid; i < NBIN; i += 256) { unsigned v = lh[i]; if (v) atomicAdd(&gh[i], v); }
}

// ---------------- threshold-bin choose (16 blocks, once) ----------------
__global__ void k_select(const unsigned* __restrict__ hist, unsigned* __restrict__ wsu) {
  int n = blockIdx.x, tid = threadIdx.x;
  const unsigned* gh = hist + n*NBIN;
  __shared__ __align__(16) unsigned lh[NBIN];
  __shared__ unsigned spp[256];
  const uint4* gh4 = (const uint4*)gh;
  unsigned ps = 0;
  #pragma unroll
  for (int k = 0; k < 4; ++k) {
    uint4 v = gh4[tid*4 + k];
    *(uint4*)&lh[tid*16 + 4*k] = v;
    ps += v.x + v.y + v.z + v.w;
  }
  spp[tid] = ps;
  __syncthreads();
  if (tid == 0) {
    const unsigned K = TOPK;
    unsigned cum = 0; int bsel = 0;
    for (int t = 255; t >= 0; --t) {
      if (cum + spp[t] >= K) {
        bsel = t*16;
        for (int b = t*16 + 15; b >= t*16; --b) {
          if (cum + lh[b] >= K) { bsel = b; break; }
          cum += lh[b];
        }
        break;
      }
      cum += spp[t];
    }
    wsu[O_BSEL + n] = (unsigned)bsel;   // plain stores to ws: fine
    wsu[O_KN + n]   = K - cum;
  }
}

// ---------------- atmospheric-light partial sums (branchless, streaming) ----------------
__global__ void __launch_bounds__(256)
k_asum(const float* __restrict__ x, const float* __restrict__ wsf,
       const unsigned* __restrict__ wsu, float* __restrict__ part) {
  __shared__ float bl[4][7];
  int tid = threadIdx.x;
  int n = blockIdx.x >> 6, chunk = blockIdx.x & 63;
  int bsel = (int)wsu[O_BSEL + n];
  const float4* db = (const float4*)(wsf + O_DARK + (size_t)n*HW + (size_t)chunk*4096);
  const float4* x0 = (const float4*)(x + (size_t)n*3*HW + (size_t)chunk*4096);
  const float4* x1 = x0 + HW/4;
  const float4* x2 = x0 + HW/2;
  float s0=0,s1=0,s2=0,e0=0,e1=0,e2=0,ec=0;
  #pragma unroll
  for (int k = 0; k < 4; ++k) {
    int idx = k*256 + tid;
    float4 d = db[idx], a = x0[idx], b = x1[idx], c = x2[idx];
    #define ACC(DX, AX, BX, CX) { \
      int bb = dark_bin(DX); \
      bool gt = (bb > bsel), eq = (bb == bsel); \
      s0 += gt ? AX : 0.f; s1 += gt ? BX : 0.f; s2 += gt ? CX : 0.f; \
      e0 += eq ? AX : 0.f; e1 += eq ? BX : 0.f; e2 += eq ? CX : 0.f; \
      ec += eq ? 1.f : 0.f; }
    ACC(d.x, a.x, b.x, c.x) ACC(d.y, a.y, b.y, c.y)
    ACC(d.z, a.z, b.z, c.z) ACC(d.w, a.w, b.w, c.w)
    #undef ACC
  }
  #pragma unroll
  for (int off = 32; off; off >>= 1) {
    s0 += __shfl_down(s0, off); s1 += __shfl_down(s1, off); s2 += __shfl_down(s2, off);
    e0 += __shfl_down(e0, off); e1 += __shfl_down(e1, off); e2 += __shfl_down(e2, off);
    ec += __shfl_down(ec, off);
  }
  int wave = tid >> 6, lane = tid & 63;
  if (lane == 0) {
    bl[wave][0]=s0; bl[wave][1]=s1; bl[wave][2]=s2;
    bl[wave][3]=e0; bl[wave][4]=e1; bl[wave][5]=e2; bl[wave][6]=ec;
  }
  __syncthreads();
  if (tid < 7) part[blockIdx.x*8 + tid] = bl[0][tid] + bl[1][tid] + bl[2][tid] + bl[3][tid];
}

// ---------------- fold partials -> A, plus param squashing ----------------
__global__ void k_areduce(const float* __restrict__ part, const unsigned* __restrict__ wsu,
                          float* __restrict__ wsf, const float* __restrict__ o1,
                          const float* __restrict__ o2) {
  int n = blockIdx.x, t = threadIdx.x;  // 64 threads = 64 chunks
  const float* p = part + (size_t)(n*64 + t)*8;
  float s0=p[0], s1=p[1], s2=p[2], e0=p[3], e1=p[4], e2=p[5], ec=p[6];
  #pragma unroll
  for (int off = 32; off; off >>= 1) {
    s0 += __shfl_down(s0, off); s1 += __shfl_down(s1, off); s2 += __shfl_down(s2, off);
    e0 += __shfl_down(e0, off); e1 += __shfl_down(e1, off); e2 += __shfl_down(e2, off);
    ec += __shfl_down(ec, off);
  }
  if (t == 0) {
    float kn = (float)wsu[O_KN + n];
    float ce = fmaxf(ec, 1.0f);
    wsf[O_A + n*3 + 0] = (s0 + kn * (e0 / ce)) * (1.0f/(float)TOPK);
    wsf[O_A + n*3 + 1] = (s1 + kn * (e1 / ce)) * (1.0f/(float)TOPK);
    wsf[O_A + n*3 + 2] = (s2 + kn * (e2 / ce)) * (1.0f/(float)TOPK);
    wsf[O_O1+n*7+0] = tanh01(o1[n*7+0])*0.25f + 1.0f;
    wsf[O_O1+n*7+1] = tanh01(o1[n*7+1])*0.9f  + 0.1f;
    wsf[O_O1+n*7+2] = tanh01(o1[n*7+2])*2.0f;
    wsf[O_O1+n*7+3] = tanh01(o1[n*7+3]);
    wsf[O_O1+n*7+4] = tanh01(o1[n*7+4])*0.1f + 0.95f;
    wsf[O_O1+n*7+5] = tanh01(o1[n*7+5])*0.1f + 0.95f;
    wsf[O_O1+n*7+6] = tanh01(o1[n*7+6])*0.1f + 0.95f;
    float q0 = expf(tanh01(o2[n*4+0]));
    float q1 = expf(tanh01(o2[n*4+1]));
    float q2 = expf(tanh01(o2[n*4+2]));
    float q3 = expf(tanh01(o2[n*4+3]));
    float s = q0+q1+q2+q3;
    q0 /= s; q1 /= s; q2 /= s; q3 /= s;
    wsf[O_O2+n*4+0]=q0; wsf[O_O2+n*4+1]=q1; wsf[O_O2+n*4+2]=q2; wsf[O_O2+n*4+3]=q3;
    wsf[O_DEN+n] = (q0+q1+q2+q3) + 0.001f;
  }
}

// ---------------- fused per-pixel kernel, float4 per thread ----------------
__global__ void __launch_bounds__(256)
k_main(const float* __restrict__ x, float* __restrict__ wsf, float* __restrict__ out) {
  __shared__ __align__(16) float xs[20*72];   // rows h0-2..h0+17, cols w0-4..w0+67
  __shared__ __align__(16) float hb[20*64];   // horizontal blur
  __shared__ float rmn[4], rmx[4];
  int tid = threadIdx.x;
  int w0 = blockIdx.x * 64, h0 = blockIdx.y * 16;
  int z = blockIdx.z, n = z / 3, c = z % 3;
  const float* xc = x + (size_t)z*HW;
  for (int i = tid; i < 360; i += 256) {
    int r = i / 18, q = i - r*18;
    int gh = h0 - 2 + r, gw = w0 - 4 + 4*q;
    float4 v; v.x = 0.f; v.y = 0.f; v.z = 0.f; v.w = 0.f;
    if (gh >= 0 && gh < HH && gw >= 0 && gw < WW)
      v = *(const float4*)&xc[(size_t)gh*WW + gw];
    *(float4*)&xs[r*72 + 4*q] = v;
  }
  __syncthreads();
  for (int i = tid; i < 320; i += 256) {
    int r = i >> 4, c4 = (i & 15) * 4;
    const float4* xr = (const float4*)&xs[r*72];
    int qb = c4 >> 2;
    float4 A4 = xr[qb], B4 = xr[qb+1], C4 = xr[qb+2];
    float m2=A4.z, m3=A4.w, m4=B4.x, m5=B4.y, m6=B4.z, m7=B4.w, m8=C4.x, m9=C4.y;
    float4 o;
    o.x = G0*(m2+m6) + G1*(m3+m5) + G2*m4;
    o.y = G0*(m3+m7) + G1*(m4+m6) + G2*m5;
    o.z = G0*(m4+m8) + G1*(m5+m7) + G2*m6;
    o.w = G0*(m5+m9) + G1*(m6+m8) + G2*m7;
    *(float4*)&hb[r*64 + c4] = o;
  }
  __syncthreads();
  float param = wsf[O_O1 + n*7 + 0];
  float lamda = wsf[O_O1 + n*7 + 2];
  float wpar  = wsf[O_O1 + n*7 + 3];
  float wb    = wsf[O_O1 + n*7 + 4 + c];
  float q0 = wsf[O_O2 + n*4 + 0], q1 = wsf[O_O2 + n*4 + 1];
  float q2 = wsf[O_O2 + n*4 + 2], q3 = wsf[O_O2 + n*4 + 3];
  float rden = 1.0f / wsf[O_DEN + n];
  float A   = wsf[O_A + n*3 + c];
  int r = tid >> 4, c4 = (tid & 15) * 4;
  float4 xv = *(const float4*)&xs[(r+2)*72 + c4 + 4];
  float4 b0 = *(const float4*)&hb[(r+0)*64 + c4];
  float4 b1 = *(const float4*)&hb[(r+1)*64 + c4];
  float4 b2 = *(const float4*)&hb[(r+2)*64 + c4];
  float4 b3 = *(const float4*)&hb[(r+3)*64 + c4];
  float4 b4 = *(const float4*)&hb[(r+4)*64 + c4];
  const float* dark = wsf + O_DARK + (size_t)n*HW;
  float4 dk = *(const float4*)&dark[(size_t)(h0+r)*WW + w0 + c4];
  float4 osum;
  float mnv = 3.4e38f, mxv = -3.4e38f;
  #define PIX(OX, XV, B0, B1, B2, B3, B4, DK) { \
    float blur = clamp01(G0*(B0+B4) + G1*(B1+B3) + G2*B2); \
    float x4v = clamp01(XV + lamda*(XV - blur)); \
    float x1v = clamp01(XV * wb); \
    float x2v = clamp01(__expf(param*__logf(XV)) + 0.001f); \
    float tr = 1.0f - wpar*DK; tr = tr > 0.1f ? tr : 0.1f; \
    float x5v = clamp01((XV - A)/(tr + 0.001f) + A); \
    OX = (XV + 0.1f*(q0*x1v + q1*x2v + q2*x4v + q3*x5v)) * rden; \
    mnv = fminf(mnv, OX); mxv = fmaxf(mxv, OX); }
  PIX(osum.x, xv.x, b0.x, b1.x, b2.x, b3.x, b4.x, dk.x)
  PIX(osum.y, xv.y, b0.y, b1.y, b2.y, b3.y, b4.y, dk.y)
  PIX(osum.z, xv.z, b0.z, b1.z, b2.z, b3.z, b4.z, dk.z)
  PIX(osum.w, xv.w, b0.w, b1.w, b2.w, b3.w, b4.w, dk.w)
  #undef PIX
  *(float4*)&out[(size_t)z*HW + (size_t)(h0+r)*WW + w0 + c4] = osum;
  #pragma unroll
  for (int off = 32; off; off >>= 1) {
    mnv = fminf(mnv, __shfl_down(mnv, off));
    mxv = fmaxf(mxv, __shfl_down(mxv, off));
  }
  int wave = tid >> 6, lane = tid & 63;
  if (lane == 0) { rmn[wave] = mnv; rmx[wave] = mxv; }
  __syncthreads();
  if (tid == 0) {
    mnv = fminf(fminf(rmn[0], rmn[1]), fminf(rmn[2], rmn[3]));
    mxv = fmaxf(fmaxf(rmx[0], rmx[1]), fmaxf(rmx[2], rmx[3]));
    int bxy = blockIdx.y * 8 + blockIdx.x;
    wsf[O_MMP + z*512 + bxy]       = mnv;   // plain stores to ws
    wsf[O_MMP + z*512 + 256 + bxy] = mxv;
  }
}

// ---------------- fold min/max partials (48 blocks, once) ----------------
__global__ void k_mmred(float* __restrict__ wsf) {
  int z = blockIdx.x, tid = threadIdx.x;
  __shared__ float rmn[4], rmx[4];
  float mn = wsf[O_MMP + z*512 + tid];
  float mx = wsf[O_MMP + z*512 + 256 + tid];
  #pragma unroll
  for (int off = 32; off; off >>= 1) {
    mn = fminf(mn, __shfl_down(mn, off));
    mx = fmaxf(mx, __shfl_down(mx, off));
  }
  int wave = tid >> 6, lane = tid & 63;
  if (lane == 0) { rmn[wave] = mn; rmx[wave] = mx; }
  __syncthreads();
  if (tid == 0) {
    wsf[O_MIN + z] = fminf(fminf(rmn[0], rmn[1]), fminf(rmn[2], rmn[3]));
    wsf[O_MAX + z] = fmaxf(fmaxf(rmx[0], rmx[1]), fmaxf(rmx[2], rmx[3]));
  }
}

// ---------------- normalization: pure stream, 8 float4/thread ----------------
__global__ void __launch_bounds__(256)
k_norm(float* __restrict__ out, const float* __restrict__ wsf) {
  int nc = blockIdx.x >> 5;          // 32 blocks per (n,c), 2048 f4 each
  int sub = blockIdx.x & 31;
  float mn = wsf[O_MIN + nc];
  float mx = wsf[O_MAX + nc];
  float sc = 1.0f / (mx - mn + 1e-7f);
  float4* o4 = (float4*)out + (size_t)nc*65536 + (size_t)sub*2048;
  int tid = threadIdx.x;
  #pragma unroll
  for (int k = 0; k < 8; ++k) {
    float4 v = o4[k*256 + tid];
    v.x = (v.x - mn) * sc; v.y = (v.y - mn) * sc;
    v.z = (v.z - mn) * sc; v.w = (v.w - mn) * sc;
    o4[k*256 + tid] = v;
  }
}

extern "C" void kernel_launch(void* const* d_in, const int* in_sizes, int n_in,
                              void* d_out, int out_size, void* d_ws, size_t ws_size,
                              hipStream_t stream) {
  const float* x  = (const float*)d_in[0];
  const float* o1 = (const float*)d_in[1];
  const float* o2 = (const float*)d_in[2];
  float* out = (float*)d_out;
  float* wsf = (float*)d_ws;
  unsigned* wsu = (unsigned*)d_ws;
  unsigned* hist = (unsigned*)(out + (size_t)16*HW);   // d_out scratch
  float* part = out + (size_t)17*HW;                   // d_out scratch

  k_zero<<<dim3(64), dim3(256), 0, stream>>>(hist);
  k_dark<<<dim3(8, 16, 16), dim3(256), 0, stream>>>(x, wsf, hist);
  k_select<<<dim3(16), dim3(256), 0, stream>>>(hist, wsu);
  k_asum<<<dim3(1024), dim3(256), 0, stream>>>(x, wsf, wsu, part);
  k_areduce<<<dim3(16), dim3(64), 0, stream>>>(part, wsu, wsf, o1, o2);
  k_main<<<dim3(8, 32, 48), dim3(256), 0, stream>>>(x, wsf, out);
  k_mmred<<<dim3(48), dim3(256), 0, stream>>>(wsf);
  k_norm<<<dim3(1536), dim3(256), 0, stream>>>(out, wsf);
}

// Round 8
// 186.914 us; speedup vs baseline: 4.5742x; 1.0443x over previous
//
#include <hip/hip_runtime.h>
#include <math.h>

#define NS   16
#define HH   512
#define WW   512
#define HW   (HH*WW)
#define TOPK 13107
#define NBIN 4096

// ---- ws word offsets. NO ATOMICS EVER TARGET d_ws (measured 100+us stalls r1/r2).
// ---- NO cooperative/persistent kernel (measured 1.1ms effective 263 GB/s, r5).
// ---- NO ballot-leader aggregation for smooth value-domain bins (r6: 157us k_dark).
// ---- Dispatch boundaries cost ~4-5us each (r7 vs r4): keep dispatch count minimal.
#define O_O1   0        // [16][7] squashed o1 params        (written k_asum, read k_main)
#define O_O2   112      // [16][4] softmax weights
#define O_DEN  176      // [16]    sum(o2)+0.001
#define O_KN   304      // [16]    remaining k within threshold bin
#define O_MMP  512      // [48][512] per-tile min(0:256)/max(256:512) partials
#define O_PART 25088    // [1024][8] asum per-block partials (plain stores only)
#define O_DARK 33280    // [16*512*512] f32 dark channel

// ---- d_out scratch (words; consumed by k_asum before k_main overwrites out):
//   hist = out + 16HW  (16x4096 u32; atomics OK here — d_out, measured fast r2-r4)

// Gaussian weights phi/(sum+0.001), hardcoded (double-derived; ref fp32 diff ~1e-8)
#define G0 0.054466787f
#define G1 0.244103071f
#define G2 0.402457854f

__device__ __forceinline__ float tanh01(float v) { return tanhf(v)*0.5f + 0.5f; }
__device__ __forceinline__ float clamp01(float v) { return fminf(fmaxf(v, 0.0f), 1.0f); }
__device__ __forceinline__ int dark_bin(float v) {
  int b = (int)(v * (float)NBIN);
  return b > (NBIN-1) ? (NBIN-1) : (b < 0 ? 0 : b);
}

// ---------------- zero histogram ----------------
__global__ void k_zero(unsigned* __restrict__ hist) {
  int i = blockIdx.x * 256 + threadIdx.x;       // 16384 uint4 = 65536 words
  uint4 z; z.x = 0u; z.y = 0u; z.z = 0u; z.w = 0u;
  ((uint4*)hist)[i] = z;
}

// ---------------- fused minc + 15x15 box filter + histogram ----------------
// block: 64x32 dark tile. grid (8,16,16).
__global__ void __launch_bounds__(256)
k_dark(const float* __restrict__ x, float* __restrict__ wsf, unsigned* __restrict__ hist) {
  __shared__ __align__(16) float sm[4096 + 46*64];   // union(minc[46*80]=3680, lh[4096]) + hsum[46*64]
  float* minc = sm;
  unsigned* lh = (unsigned*)sm;
  float* hsum = sm + 4096;
  int tid = threadIdx.x;
  int w0 = blockIdx.x * 64, h0 = blockIdx.y * 32, n = blockIdx.z;
  const float* xb = x + (size_t)n*3*HW;

  // stage minc rows [h0-7,h0+39) cols [w0-8,w0+72), zero outside (box filter zero-pads)
  for (int i = tid; i < 46*20; i += 256) {
    int r = i / 20, q = i - r*20;
    int hm = h0 - 7 + r, wc = w0 - 8 + 4*q;
    float4 v; v.x = 0.f; v.y = 0.f; v.z = 0.f; v.w = 0.f;
    if (hm >= 0 && hm < HH && wc >= 0 && wc < WW) {
      size_t o = (size_t)hm*WW + wc;
      float4 a = *(const float4*)&xb[o];
      float4 b = *(const float4*)&xb[HW + o];
      float4 c = *(const float4*)&xb[2*HW + o];
      v.x = fminf(fminf(a.x,b.x),c.x); v.y = fminf(fminf(a.y,b.y),c.y);
      v.z = fminf(fminf(a.z,b.z),c.z); v.w = fminf(fminf(a.w,b.w),c.w);
    }
    *(float4*)&minc[r*80 + 4*q] = v;
  }
  __syncthreads();
  // horizontal 15-tap sum
  for (int i = tid; i < 46*16; i += 256) {
    int r = i >> 4, c4 = (i & 15) * 4;
    const float4* mr = (const float4*)&minc[r*80];
    int qb = c4 >> 2;
    float m[20];
    #pragma unroll
    for (int t = 0; t < 5; ++t) {
      float4 v = mr[qb + t];
      m[4*t] = v.x; m[4*t+1] = v.y; m[4*t+2] = v.z; m[4*t+3] = v.w;
    }
    float s = 0.f;
    #pragma unroll
    for (int j = 1; j <= 15; ++j) s += m[j];
    float4 o;
    o.x = s; s += m[16] - m[1];
    o.y = s; s += m[17] - m[2];
    o.z = s; s += m[18] - m[3];
    o.w = s;
    *(float4*)&hsum[r*64 + c4] = o;
  }
  __syncthreads();
  for (int i = tid; i < NBIN; i += 256) lh[i] = 0u;   // minc dead; reuse as hist
  __syncthreads();
  // vertical 15-tap sliding sum -> dark; plain per-pixel LDS atomics (r4-proven fast)
  {
    int c = tid & 63, ty = tid >> 6, r0 = ty * 8;
    float s = 0.f;
    #pragma unroll
    for (int j = 0; j < 15; ++j) s += hsum[(r0 + j)*64 + c];
    float* dk = wsf + O_DARK + (size_t)n*HW;
    #pragma unroll
    for (int i = 0; i < 8; ++i) {
      int r = r0 + i;
      float v = s * (1.0f/225.0f);
      dk[(size_t)(h0 + r)*WW + w0 + c] = v;
      atomicAdd(&lh[dark_bin(v)], 1u);
      if (i < 7) s += hsum[(r + 15)*64 + c] - hsum[r*64 + c];
    }
  }
  __syncthreads();
  unsigned* gh = hist + n*NBIN;
  for (int i = tid; i < NBIN; i += 256) { unsigned v = lh[i]; if (v) atomicAdd(&gh[i], v); }
}

// ---------------- fused select head + atmospheric partial sums + params ----------------
__global__ void __launch_bounds__(256)
k_asum(const float* __restrict__ x, float* __restrict__ wsf,
       const unsigned* __restrict__ hist, unsigned* __restrict__ wsu,
       const float* __restrict__ o1, const float* __restrict__ o2) {
  __shared__ __align__(16) unsigned lh[NBIN];
  __shared__ unsigned spp[256];
  __shared__ int sh_bsel;
  __shared__ float bl[4][7];
  int tid = threadIdx.x;
  int n = blockIdx.x >> 6, chunk = blockIdx.x & 63;
  // select head: load hist (L2-hot) + redundant per-block scan (~1us, r4-proven)
  const uint4* gh4 = (const uint4*)(hist + n*NBIN);
  unsigned ps = 0;
  #pragma unroll
  for (int k = 0; k < 4; ++k) {
    uint4 v = gh4[tid*4 + k];
    *(uint4*)&lh[tid*16 + 4*k] = v;
    ps += v.x + v.y + v.z + v.w;
  }
  spp[tid] = ps;
  __syncthreads();
  if (tid == 0) {
    const unsigned K = TOPK;
    unsigned cum = 0; int bsel = 0;
    for (int t = 255; t >= 0; --t) {
      if (cum + spp[t] >= K) {
        bsel = t*16;
        for (int b = t*16 + 15; b >= t*16; --b) {
          if (cum + lh[b] >= K) { bsel = b; break; }
          cum += lh[b];
        }
        break;
      }
      cum += spp[t];
    }
    sh_bsel = bsel;
    if (chunk == 0) {
      wsu[O_KN + n] = K - cum;   // plain store to ws
      // param squashing for this n (single writer; consumed by k_main next dispatch)
      wsf[O_O1+n*7+0] = tanh01(o1[n*7+0])*0.25f + 1.0f;
      wsf[O_O1+n*7+1] = tanh01(o1[n*7+1])*0.9f  + 0.1f;
      wsf[O_O1+n*7+2] = tanh01(o1[n*7+2])*2.0f;
      wsf[O_O1+n*7+3] = tanh01(o1[n*7+3]);
      wsf[O_O1+n*7+4] = tanh01(o1[n*7+4])*0.1f + 0.95f;
      wsf[O_O1+n*7+5] = tanh01(o1[n*7+5])*0.1f + 0.95f;
      wsf[O_O1+n*7+6] = tanh01(o1[n*7+6])*0.1f + 0.95f;
      float q0 = expf(tanh01(o2[n*4+0]));
      float q1 = expf(tanh01(o2[n*4+1]));
      float q2 = expf(tanh01(o2[n*4+2]));
      float q3 = expf(tanh01(o2[n*4+3]));
      float s = q0+q1+q2+q3;
      q0 /= s; q1 /= s; q2 /= s; q3 /= s;
      wsf[O_O2+n*4+0]=q0; wsf[O_O2+n*4+1]=q1; wsf[O_O2+n*4+2]=q2; wsf[O_O2+n*4+3]=q3;
      wsf[O_DEN+n] = (q0+q1+q2+q3) + 0.001f;
    }
  }
  __syncthreads();
  int bsel = sh_bsel;
  // branchless f4 partial sums over this 4096-element chunk
  const float4* db = (const float4*)(wsf + O_DARK + (size_t)n*HW + (size_t)chunk*4096);
  const float4* x0 = (const float4*)(x + (size_t)n*3*HW + (size_t)chunk*4096);
  const float4* x1 = x0 + HW/4;
  const float4* x2 = x0 + HW/2;
  float s0=0,s1=0,s2=0,e0=0,e1=0,e2=0,ec=0;
  #pragma unroll
  for (int k = 0; k < 4; ++k) {
    int idx = k*256 + tid;
    float4 d = db[idx], a = x0[idx], b = x1[idx], c = x2[idx];
    #define ACC(DX, AX, BX, CX) { \
      int bb = dark_bin(DX); \
      bool gt = (bb > bsel), eq = (bb == bsel); \
      s0 += gt ? AX : 0.f; s1 += gt ? BX : 0.f; s2 += gt ? CX : 0.f; \
      e0 += eq ? AX : 0.f; e1 += eq ? BX : 0.f; e2 += eq ? CX : 0.f; \
      ec += eq ? 1.f : 0.f; }
    ACC(d.x, a.x, b.x, c.x) ACC(d.y, a.y, b.y, c.y)
    ACC(d.z, a.z, b.z, c.z) ACC(d.w, a.w, b.w, c.w)
    #undef ACC
  }
  #pragma unroll
  for (int off = 32; off; off >>= 1) {
    s0 += __shfl_down(s0, off); s1 += __shfl_down(s1, off); s2 += __shfl_down(s2, off);
    e0 += __shfl_down(e0, off); e1 += __shfl_down(e1, off); e2 += __shfl_down(e2, off);
    ec += __shfl_down(ec, off);
  }
  int wave = tid >> 6, lane = tid & 63;
  if (lane == 0) {
    bl[wave][0]=s0; bl[wave][1]=s1; bl[wave][2]=s2;
    bl[wave][3]=e0; bl[wave][4]=e1; bl[wave][5]=e2; bl[wave][6]=ec;
  }
  __syncthreads();
  if (tid < 7) wsf[O_PART + blockIdx.x*8 + tid] =
      bl[0][tid] + bl[1][tid] + bl[2][tid] + bl[3][tid];   // plain store to ws
}

// ---------------- fused per-pixel kernel (A-reduce head), float4 per thread ----------------
__global__ void __launch_bounds__(256)
k_main(const float* __restrict__ x, float* __restrict__ wsf,
       const unsigned* __restrict__ wsu, float* __restrict__ out) {
  __shared__ __align__(16) float xs[20*72];   // rows h0-2..h0+17, cols w0-4..w0+67
  __shared__ __align__(16) float hb[20*64];   // horizontal blur
  __shared__ float rmn[4], rmx[4];
  __shared__ float shA;
  int tid = threadIdx.x;
  int w0 = blockIdx.x * 64, h0 = blockIdx.y * 16;
  int z = blockIdx.z, n = z / 3, c = z % 3;
  const float* xc = x + (size_t)z*HW;
  for (int i = tid; i < 360; i += 256) {
    int r = i / 18, q = i - r*18;
    int gh = h0 - 2 + r, gw = w0 - 4 + 4*q;
    float4 v; v.x = 0.f; v.y = 0.f; v.z = 0.f; v.w = 0.f;
    if (gh >= 0 && gh < HH && gw >= 0 && gw < WW)
      v = *(const float4*)&xc[(size_t)gh*WW + gw];
    *(float4*)&xs[r*72 + 4*q] = v;
  }
  // A-reduce head on wave 0: channel-c partials from previous dispatch (race-free)
  if (tid < 64) {
    const float* p = wsf + O_PART + (size_t)(n*64 + tid)*8;
    float sc_ = p[c], ec_ = p[3 + c], cc_ = p[6];
    #pragma unroll
    for (int off = 32; off; off >>= 1) {
      sc_ += __shfl_down(sc_, off);
      ec_ += __shfl_down(ec_, off);
      cc_ += __shfl_down(cc_, off);
    }
    if (tid == 0) {
      float kn = (float)wsu[O_KN + n];
      float ce = fmaxf(cc_, 1.0f);
      shA = (sc_ + kn * (ec_ / ce)) * (1.0f/(float)TOPK);
    }
  }
  __syncthreads();
  for (int i = tid; i < 320; i += 256) {
    int r = i >> 4, c4 = (i & 15) * 4;
    const float4* xr = (const float4*)&xs[r*72];
    int qb = c4 >> 2;
    float4 A4 = xr[qb], B4 = xr[qb+1], C4 = xr[qb+2];
    float m2=A4.z, m3=A4.w, m4=B4.x, m5=B4.y, m6=B4.z, m7=B4.w, m8=C4.x, m9=C4.y;
    float4 o;
    o.x = G0*(m2+m6) + G1*(m3+m5) + G2*m4;
    o.y = G0*(m3+m7) + G1*(m4+m6) + G2*m5;
    o.z = G0*(m4+m8) + G1*(m5+m7) + G2*m6;
    o.w = G0*(m5+m9) + G1*(m6+m8) + G2*m7;
    *(float4*)&hb[r*64 + c4] = o;
  }
  __syncthreads();
  float param = wsf[O_O1 + n*7 + 0];
  float lamda = wsf[O_O1 + n*7 + 2];
  float wpar  = wsf[O_O1 + n*7 + 3];
  float wb    = wsf[O_O1 + n*7 + 4 + c];
  float q0 = wsf[O_O2 + n*4 + 0], q1 = wsf[O_O2 + n*4 + 1];
  float q2 = wsf[O_O2 + n*4 + 2], q3 = wsf[O_O2 + n*4 + 3];
  float rden = 1.0f / wsf[O_DEN + n];
  float A = shA;
  int r = tid >> 4, c4 = (tid & 15) * 4;
  float4 xv = *(const float4*)&xs[(r+2)*72 + c4 + 4];
  float4 b0 = *(const float4*)&hb[(r+0)*64 + c4];
  float4 b1 = *(const float4*)&hb[(r+1)*64 + c4];
  float4 b2 = *(const float4*)&hb[(r+2)*64 + c4];
  float4 b3 = *(const float4*)&hb[(r+3)*64 + c4];
  float4 b4 = *(const float4*)&hb[(r+4)*64 + c4];
  const float* dark = wsf + O_DARK + (size_t)n*HW;
  float4 dk = *(const float4*)&dark[(size_t)(h0+r)*WW + w0 + c4];
  float4 osum;
  float mnv = 3.4e38f, mxv = -3.4e38f;
  #define PIX(OX, XV, B0, B1, B2, B3, B4, DK) { \
    float blur = clamp01(G0*(B0+B4) + G1*(B1+B3) + G2*B2); \
    float x4v = clamp01(XV + lamda*(XV - blur)); \
    float x1v = clamp01(XV * wb); \
    float x2v = clamp01(__expf(param*__logf(XV)) + 0.001f); \
    float tr = 1.0f - wpar*DK; tr = tr > 0.1f ? tr : 0.1f; \
    float x5v = clamp01((XV - A) * __builtin_amdgcn_rcpf(tr + 0.001f) + A); \
    OX = (XV + 0.1f*(q0*x1v + q1*x2v + q2*x4v + q3*x5v)) * rden; \
    mnv = fminf(mnv, OX); mxv = fmaxf(mxv, OX); }
  PIX(osum.x, xv.x, b0.x, b1.x, b2.x, b3.x, b4.x, dk.x)
  PIX(osum.y, xv.y, b0.y, b1.y, b2.y, b3.y, b4.y, dk.y)
  PIX(osum.z, xv.z, b0.z, b1.z, b2.z, b3.z, b4.z, dk.z)
  PIX(osum.w, xv.w, b0.w, b1.w, b2.w, b3.w, b4.w, dk.w)
  #undef PIX
  *(float4*)&out[(size_t)z*HW + (size_t)(h0+r)*WW + w0 + c4] = osum;
  #pragma unroll
  for (int off = 32; off; off >>= 1) {
    mnv = fminf(mnv, __shfl_down(mnv, off));
    mxv = fmaxf(mxv, __shfl_down(mxv, off));
  }
  int wave = tid >> 6, lane = tid & 63;
  if (lane == 0) { rmn[wave] = mnv; rmx[wave] = mxv; }
  __syncthreads();
  if (tid == 0) {
    mnv = fminf(fminf(rmn[0], rmn[1]), fminf(rmn[2], rmn[3]));
    mxv = fmaxf(fmaxf(rmx[0], rmx[1]), fmaxf(rmx[2], rmx[3]));
    int bxy = blockIdx.y * 8 + blockIdx.x;
    wsf[O_MMP + z*512 + bxy]       = mnv;   // plain stores to ws
    wsf[O_MMP + z*512 + 256 + bxy] = mxv;
  }
}

// ---------------- fused min/max fold head + streaming normalization ----------------
__global__ void __launch_bounds__(256)
k_norm(float* __restrict__ out, const float* __restrict__ wsf) {
  __shared__ float rmn[4], rmx[4];
  int tid = threadIdx.x;
  int nc = blockIdx.x >> 5;          // 32 blocks per (n,c), 2048 f4 each
  int sub = blockIdx.x & 31;
  // redundant per-block fold of 512 partials (L2-hot)
  float mn = wsf[O_MMP + nc*512 + tid];
  float mx = wsf[O_MMP + nc*512 + 256 + tid];
  #pragma unroll
  for (int off = 32; off; off >>= 1) {
    mn = fminf(mn, __shfl_down(mn, off));
    mx = fmaxf(mx, __shfl_down(mx, off));
  }
  int wave = tid >> 6, lane = tid & 63;
  if (lane == 0) { rmn[wave] = mn; rmx[wave] = mx; }
  __syncthreads();
  mn = fminf(fminf(rmn[0], rmn[1]), fminf(rmn[2], rmn[3]));
  mx = fmaxf(fmaxf(rmx[0], rmx[1]), fmaxf(rmx[2], rmx[3]));
  float sc = 1.0f / (mx - mn + 1e-7f);
  float4* o4 = (float4*)out + (size_t)nc*65536 + (size_t)sub*2048;
  #pragma unroll
  for (int k = 0; k < 8; ++k) {
    float4 v = o4[k*256 + tid];
    v.x = (v.x - mn) * sc; v.y = (v.y - mn) * sc;
    v.z = (v.z - mn) * sc; v.w = (v.w - mn) * sc;
    o4[k*256 + tid] = v;
  }
}

extern "C" void kernel_launch(void* const* d_in, const int* in_sizes, int n_in,
                              void* d_out, int out_size, void* d_ws, size_t ws_size,
                              hipStream_t stream) {
  const float* x  = (const float*)d_in[0];
  const float* o1 = (const float*)d_in[1];
  const float* o2 = (const float*)d_in[2];
  float* out = (float*)d_out;
  float* wsf = (float*)d_ws;
  unsigned* wsu = (unsigned*)d_ws;
  unsigned* hist = (unsigned*)(out + (size_t)16*HW);   // d_out scratch (atomics OK)

  k_zero<<<dim3(64), dim3(256), 0, stream>>>(hist);
  k_dark<<<dim3(8, 16, 16), dim3(256), 0, stream>>>(x, wsf, hist);
  k_asum<<<dim3(1024), dim3(256), 0, stream>>>(x, wsf, hist, wsu, o1, o2);
  k_main<<<dim3(8, 32, 48), dim3(256), 0, stream>>>(x, wsf, wsu, out);
  k_norm<<<dim3(1536), dim3(256), 0, stream>>>(out, wsf);
}